// Round 8
// baseline (54.602 us; speedup 1.0000x reference)
//
#include <hip/hip_runtime.h>

#define NB 4
#define NV 256
#define NF 256
#define IMG 128

typedef float v2f __attribute__((ext_vector_type(2)));
#define CONST_AS __attribute__((address_space(4)))

__device__ __forceinline__ float rcpf(float x) { return __builtin_amdgcn_rcpf(x); }
__device__ __forceinline__ float ex2(float x)  { return __builtin_amdgcn_exp2f(x); }
__device__ __forceinline__ float med01(float x) { return __builtin_amdgcn_fmed3f(x, 0.0f, 1.0f); }

// constants
#define SCV   120.11224139682566f    // sqrt((1/SIGMA)*log2(e))
#define ISC2  6.931471805599453e-05f // 1/KSIG
#define KGAMV 14.426950408889634f    // (1/GAMMA)*log2(e)

// ws layout (float units):
//   rec   @ 0      : [4][256][16]  (64 KB)   face records
//   masks @ 16384  : [4096] uint   (16 KB)   per-(b,tile,chunk) 16-bit face masks
//   part  @ 32768  : [4096][5][256] (21 MB)  per-chunk-block partials {P,S,R0,R1,R2}
//
// record: 0 a0x*SC 1 a0y*SC 2 e01x*SC 3 e01y*SC 4 e12x*SC 5 e12y*SC
//         6 ib01/KSIG 7 ib12/KSIG 8 ib20/KSIG 9 idn/KSIG 10 z0 11 z1 12 z2 13 cr 14 cg 15 cb

__global__ void prep_bin(const float* __restrict__ verts,
                         const int* __restrict__ faces,
                         const float* __restrict__ colors,
                         const float* __restrict__ eye,
                         float* __restrict__ ws)
{
    __shared__ float4 sBB[256];

    const int b = blockIdx.x;       // 0..3
    const int f = threadIdx.x;      // 0..255

    const float fpj = 1.7320508075688772f;   // 1/tan(30deg)
    const float p22 = -1.0202020202020203f;  // (far+near)/(near-far)
    const float p23 = -0.20202020202020202f; // 2*far*near/(near-far)

    float ex = eye[b*3+0], ey = eye[b*3+1], ez = eye[b*3+2];
    float en  = sqrtf(ex*ex + ey*ey + ez*ez);
    float izn = 1.0f / (en + 1e-8f);
    float zx = ex*izn, zy = ey*izn, zz = ez*izn;
    float cn  = sqrtf(zz*zz + zx*zx);
    float ixn = 1.0f / (cn + 1e-8f);
    float xx = zz*ixn, xy = 0.0f, xz = -zx*ixn;
    float yx = zy*xz - zz*xy;
    float yy = zz*xx - zx*xz;
    float yz = zx*xy - zy*xx;
    float tx = -(xx*ex + xy*ey + xz*ez);
    float ty = -(yx*ex + yy*ey + yz*ez);
    float tz = -(zx*ex + zy*ey + zz*ez);

    int i0 = faces[f*3+0], i1 = faces[f*3+1], i2 = faces[f*3+2];
    int idx[3] = { i0, i1, i2 };

    float ax[3], ay[3], az[3];
#pragma unroll
    for (int k = 0; k < 3; ++k) {
        const float* v = verts + (b*NV + idx[k])*3;
        float vx = v[0], vy = v[1], vz = v[2];
        float cx  = fpj*(xx*vx + xy*vy + xz*vz + tx);
        float cyv = fpj*(yx*vx + yy*vy + yz*vz + ty);
        float zv  = zx*vx + zy*vy + zz*vz + tz;
        float cz  = p22*zv + p23;
        float cw  = -zv;
        float iw  = 1.0f / (cw + 1e-8f);
        ax[k] = cx*iw; ay[k] = cyv*iw; az[k] = cz*iw;
    }

    float a0x = ax[0], a0y = ay[0];
    float a1x = ax[1], a1y = ay[1];
    float a2x = ax[2], a2y = ay[2];

    float e01x = a1x - a0x, e01y = a1y - a0y;
    float e12x = a2x - a1x, e12y = a2y - a1y;
    float e20x = a0x - a2x, e20y = a0y - a2y;

    float area  = e01x*(a2y - a0y) - e01y*(a2x - a0x);
    float denom = area + (area >= 0.0f ? 1e-12f : -1e-12f);
    float idn   = 1.0f / denom;

    float ib01 = 1.0f / (e01x*e01x + e01y*e01y + 1e-12f);
    float ib12 = 1.0f / (e12x*e12x + e12y*e12y + 1e-12f);
    float ib20 = 1.0f / (e20x*e20x + e20y*e20y + 1e-12f);

    const float third = (1.0f/3.0f);
    float cr = (colors[(b*NV+i0)*3+0] + colors[(b*NV+i1)*3+0] + colors[(b*NV+i2)*3+0]) * third;
    float cg = (colors[(b*NV+i0)*3+1] + colors[(b*NV+i1)*3+1] + colors[(b*NV+i2)*3+1]) * third;
    float cb = (colors[(b*NV+i0)*3+2] + colors[(b*NV+i1)*3+2] + colors[(b*NV+i2)*3+2]) * third;

    float* o = ws + (((b<<8) + f) << 4);
    ((float4*)o)[0] = make_float4(a0x*SCV,   a0y*SCV,   e01x*SCV,  e01y*SCV);
    ((float4*)o)[1] = make_float4(e12x*SCV,  e12y*SCV,  ib01*ISC2, ib12*ISC2);
    ((float4*)o)[2] = make_float4(ib20*ISC2, idn*ISC2,  az[0],     az[1]);
    ((float4*)o)[3] = make_float4(az[2],     cr,        cg,        cb);

    // pixel-space bbox with 4px margin (safe skip needs > 3.02 px)
    float xmn = fminf(fminf(a0x, a1x), a2x);
    float xmx = fmaxf(fmaxf(a0x, a1x), a2x);
    float ymn = fminf(fminf(a0y, a1y), a2y);
    float ymx = fmaxf(fmaxf(a0y, a1y), a2y);
    // w = (x_ndc+1)*64 - 0.5 ; h = (1-y_ndc)*64 - 0.5 ; margin 0.0625 NDC = 4 px
    sBB[f] = make_float4((xmn + 0.9375f)*64.0f - 0.5f,   // wmin
                         (xmx + 1.0625f)*64.0f - 0.5f,   // wmax
                         (0.9375f - ymx)*64.0f - 0.5f,   // hmin
                         (1.0625f - ymn)*64.0f - 0.5f);  // hmax
    __syncthreads();

    // one thread per 16x16 tile builds 16 chunk masks (deterministic)
    if (f < 64) {
        const int tile = f;
        const float tX0 = (float)((tile & 7) << 4);
        const float tY0 = (float)((tile >> 3) << 4);
        const float tX1 = tX0 + 15.0f;
        const float tY1 = tY0 + 15.0f;
        unsigned* mk = (unsigned*)(ws + 16384) + (((b << 6) + tile) << 4);
        unsigned m = 0;
        for (int ff = 0; ff < 256; ++ff) {
            float4 bb = sBB[ff];
            bool hit = (bb.x <= tX1) && (bb.y >= tX0) && (bb.z <= tY1) && (bb.w >= tY0);
            m |= (hit ? 1u : 0u) << (ff & 15);
            if ((ff & 15) == 15) { mk[ff >> 4] = m; m = 0; }
        }
    }
}

// grid 4096 = b*1024 + tile*16 + chunk; 256 threads = 1 px each (4 waves)
__launch_bounds__(256)
__global__ void raster(const float* __restrict__ ws, float* __restrict__ part)
{
    const int bid = blockIdx.x;
    const int t   = threadIdx.x;

    const unsigned mask =
        *((const CONST_AS unsigned*)(unsigned long long)((const unsigned*)(ws + 16384) + bid));

    float P = 1.0f, S = 0.0f, R0 = 0.0f, R1 = 0.0f, R2 = 0.0f;

    if (mask) {
        const int b = bid >> 10, tile = (bid >> 4) & 63, chunk = bid & 15;
        const int tx0 = (tile & 7) << 4, ty0 = (tile >> 3) << 4;
        const int w = tx0 + (t & 15), h = ty0 + (t >> 4);
        const float xs = ((w + 0.5f) * (1.0f/64.0f) - 1.0f) * SCV;
        const float ys = (1.0f - (h + 0.5f) * (1.0f/64.0f)) * SCV;
        const float* recb = ws + (((b << 8) + (chunk << 4)) << 4);

#pragma unroll
        for (int i = 0; i < 16; ++i) {
            if (mask & (1u << i)) {
                const CONST_AS float* c =
                    (const CONST_AS float*)(unsigned long long)(recb + (i << 4));
                float a0x = c[0],  a0y = c[1];
                float e01x = c[2], e01y = c[3];
                float e12x = c[4], e12y = c[5];
                float ib01 = c[6], ib12 = c[7], ib20 = c[8];
                float idn = c[9];
                float z0 = c[10], z1 = c[11], z2 = c[12];
                float cr = c[13], cg = c[14], cb = c[15];

                float e20x = -(e01x + e12x), e20y = -(e01y + e12y);
                float g01x = e01x*ib01, g01y = e01y*ib01;
                float g12x = e12x*ib12, g12y = e12y*ib12;
                float g20x = e20x*ib20, g20y = e20y*ib20;

                float pa0x = xs - a0x, pa0y = ys - a0y;
                float pa1x = pa0x - e01x, pa1y = pa0y - e01y;
                float pa2x = pa0x + e20x, pa2y = pa0y + e20y;

                float b0 = (e12x*pa1y - e12y*pa1x) * idn;
                float b1 = (e20x*pa2y - e20y*pa2x) * idn;
                float b2 = (e01x*pa0y - e01y*pa0x) * idn;

                float tt = med01(fmaf(pa0x, g01x, pa0y*g01y));
                float dx = fmaf(-tt, e01x, pa0x);
                float dy = fmaf(-tt, e01y, pa0y);
                float dd0 = fmaf(dx, dx, dy*dy);

                tt = med01(fmaf(pa1x, g12x, pa1y*g12y));
                dx = fmaf(-tt, e12x, pa1x);
                dy = fmaf(-tt, e12y, pa1y);
                float dd1 = fmaf(dx, dx, dy*dy);

                tt = med01(fmaf(pa2x, g20x, pa2y*g20y));
                dx = fmaf(-tt, e20x, pa2x);
                dy = fmaf(-tt, e20y, pa2y);
                float dd2 = fmaf(dx, dx, dy*dy);

                float dd = fminf(fminf(dd0, dd1), dd2);
                float mx = fmaxf(fmaxf(-b0, -b1), -b2);
                float q  = copysignf(dd, mx);

                float prob = rcpf(1.0f + ex2(q));
                P = fmaf(-prob, P, P);

                float bc0 = med01(b0), bc1 = med01(b1), bc2 = med01(b2);
                float s  = bc0 + bc1 + bc2 + 1e-8f;
                float zs = fmaf(bc0, z0, fmaf(bc1, z1, bc2*z2));
                float zq = fmaf(zs * rcpf(s), -0.5f*KGAMV, 0.5f*KGAMV);
                float ez = ex2(__builtin_amdgcn_fmed3f(zq, 0.0f, KGAMV));
                float wgt = prob * ez;

                S  += wgt;
                R0 = fmaf(wgt, cr, R0);
                R1 = fmaf(wgt, cg, R1);
                R2 = fmaf(wgt, cb, R2);
            }
        }
    }

    float* pout = part + bid*1280;
    pout[t]        = P;
    pout[256  + t] = S;
    pout[512  + t] = R0;
    pout[768  + t] = R1;
    pout[1024 + t] = R2;
}

// grid 256 = b*64 + tile; 256 threads = 1 px each
__launch_bounds__(256)
__global__ void combine(const float* __restrict__ part, float* __restrict__ out)
{
    const int bt = blockIdx.x;
    const int t  = threadIdx.x;
    const float* pb = part + bt*20480;

    float P = 1.0f, S = 0.0f, R0 = 0.0f, R1 = 0.0f, R2 = 0.0f;
#pragma unroll
    for (int c = 0; c < 16; ++c) {
        const float* q = pb + c*1280;
        P  *= q[t];
        S  += q[256  + t];
        R0 += q[512  + t];
        R1 += q[768  + t];
        R2 += q[1024 + t];
    }
    float iden = rcpf(S + 1.0f);   // background weight = exp2(0) = 1

    const int b = bt >> 6, tile = bt & 63;
    const int w = ((tile & 7) << 4) + (t & 15);
    const int h = ((tile >> 3) << 4) + (t >> 4);
    const int pix = h*IMG + w;

    out[b*16384 + pix] = 1.0f - P;
    float* rgb = out + 65536;
    rgb[(b*3 + 0)*16384 + pix] = R0 * iden;
    rgb[(b*3 + 1)*16384 + pix] = R1 * iden;
    rgb[(b*3 + 2)*16384 + pix] = R2 * iden;
}

extern "C" void kernel_launch(void* const* d_in, const int* in_sizes, int n_in,
                              void* d_out, int out_size, void* d_ws, size_t ws_size,
                              hipStream_t stream)
{
    const float* verts  = (const float*)d_in[0];
    const int*   faces  = (const int*)d_in[1];
    const float* colors = (const float*)d_in[2];
    const float* eye    = (const float*)d_in[3];
    float* out = (float*)d_out;
    float* ws  = (float*)d_ws;      // rec @0, masks @16384, part @32768 (~21.1 MB total)
    float* part = ws + 32768;

    hipLaunchKernelGGL(prep_bin, dim3(4),    dim3(256), 0, stream, verts, faces, colors, eye, ws);
    hipLaunchKernelGGL(raster,   dim3(4096), dim3(256), 0, stream, ws, part);
    hipLaunchKernelGGL(combine,  dim3(256),  dim3(256), 0, stream, part, out);
}

// Round 9
// 53.142 us; speedup vs baseline: 1.0275x; 1.0275x over previous
//
#include <hip/hip_runtime.h>

#define NB 4
#define NV 256
#define NF 256
#define IMG 128
#define STR 32   // floats per face-PAIR record (16 values x 2, 128B)

typedef float v2f __attribute__((ext_vector_type(2)));

__device__ __forceinline__ float rcpf(float x) { return __builtin_amdgcn_rcpf(x); }
__device__ __forceinline__ float ex2(float x)  { return __builtin_amdgcn_exp2f(x); }
__device__ __forceinline__ float med01(float x) { return __builtin_amdgcn_fmed3f(x, 0.0f, 1.0f); }
__device__ __forceinline__ v2f med01_2(v2f v) { return (v2f){ med01(v.x), med01(v.y) }; }
__device__ __forceinline__ v2f fma2(v2f a, v2f b, v2f c) { return __builtin_elementwise_fma(a, b, c); }
__device__ __forceinline__ int rfl(int x) { return __builtin_amdgcn_readfirstlane(x); }

#define SCV   120.11224139682566f    // sqrt((1/SIGMA)*log2(e))
#define ISC2  6.931471805599453e-05f // 1/KSIG
#define KGAMV 14.426950408889634f    // (1/GAMMA)*log2(e)

// ws layout (float units):
//   rec   @ 0     : [4][128 pairs][32]  (64 KB)  pair-interleaved records (R7 layout)
//   lists @ 16384 : int[4][256 tiles][132]       (540 KB)  [0]=count, [1..]=pair idx

__global__ void prep_faces(const float* __restrict__ verts,
                           const int* __restrict__ faces,
                           const float* __restrict__ colors,
                           const float* __restrict__ eye,
                           float* __restrict__ ws)
{
    __shared__ float4 sBB[256];

    const int b = blockIdx.x;      // 0..3
    const int f = threadIdx.x;     // 0..255

    const float fpj = 1.7320508075688772f;
    const float p22 = -1.0202020202020203f;
    const float p23 = -0.20202020202020202f;

    float ex = eye[b*3+0], ey = eye[b*3+1], ez = eye[b*3+2];
    float en  = sqrtf(ex*ex + ey*ey + ez*ez);
    float izn = 1.0f / (en + 1e-8f);
    float zx = ex*izn, zy = ey*izn, zz = ez*izn;
    float cn  = sqrtf(zz*zz + zx*zx);
    float ixn = 1.0f / (cn + 1e-8f);
    float xx = zz*ixn, xy = 0.0f, xz = -zx*ixn;
    float yx = zy*xz - zz*xy;
    float yy = zz*xx - zx*xz;
    float yz = zx*xy - zy*xx;
    float tx = -(xx*ex + xy*ey + xz*ez);
    float ty = -(yx*ex + yy*ey + yz*ez);
    float tz = -(zx*ex + zy*ey + zz*ez);

    int i0 = faces[f*3+0], i1 = faces[f*3+1], i2 = faces[f*3+2];
    int idx[3] = { i0, i1, i2 };

    float ax[3], ay[3], az[3];
#pragma unroll
    for (int k = 0; k < 3; ++k) {
        const float* v = verts + (b*NV + idx[k])*3;
        float vx = v[0], vy = v[1], vz = v[2];
        float cx  = fpj*(xx*vx + xy*vy + xz*vz + tx);
        float cyv = fpj*(yx*vx + yy*vy + yz*vz + ty);
        float zv  = zx*vx + zy*vy + zz*vz + tz;
        float cz  = p22*zv + p23;
        float cw  = -zv;
        float iw  = 1.0f / (cw + 1e-8f);
        ax[k] = cx*iw; ay[k] = cyv*iw; az[k] = cz*iw;
    }

    float a0x = ax[0], a0y = ay[0];
    float a1x = ax[1], a1y = ay[1];
    float a2x = ax[2], a2y = ay[2];

    float e01x = a1x - a0x, e01y = a1y - a0y;
    float e12x = a2x - a1x, e12y = a2y - a1y;
    float e20x = a0x - a2x, e20y = a0y - a2y;

    float area  = e01x*(a2y - a0y) - e01y*(a2x - a0x);
    float denom = area + (area >= 0.0f ? 1e-12f : -1e-12f);
    float idn   = 1.0f / denom;

    float ib01 = 1.0f / (e01x*e01x + e01y*e01y + 1e-12f);
    float ib12 = 1.0f / (e12x*e12x + e12y*e12y + 1e-12f);
    float ib20 = 1.0f / (e20x*e20x + e20y*e20y + 1e-12f);

    const float third = (1.0f/3.0f);
    float cr = (colors[(b*NV+i0)*3+0] + colors[(b*NV+i1)*3+0] + colors[(b*NV+i2)*3+0]) * third;
    float cg = (colors[(b*NV+i0)*3+1] + colors[(b*NV+i1)*3+1] + colors[(b*NV+i2)*3+1]) * third;
    float cb = (colors[(b*NV+i0)*3+2] + colors[(b*NV+i1)*3+2] + colors[(b*NV+i2)*3+2]) * third;

    // pair-interleaved record (R7 layout), geometry pre-scaled
    float* o = ws + (b*128 + (f >> 1))*STR + (f & 1);
    o[ 0]=a0x*SCV;   o[ 2]=a0y*SCV;
    o[ 4]=e01x*SCV;  o[ 6]=e01y*SCV;
    o[ 8]=e12x*SCV;  o[10]=e12y*SCV;
    o[12]=ib01*ISC2; o[14]=ib12*ISC2; o[16]=ib20*ISC2;
    o[18]=idn*ISC2;
    o[20]=az[0]; o[22]=az[1]; o[24]=az[2];
    o[26]=cr;   o[28]=cg;   o[30]=cb;

    // pixel-space bbox with 4px margin (safe cutoff is 3.02px at sigma=1e-4)
    float xmn = fminf(fminf(a0x, a1x), a2x);
    float xmx = fmaxf(fmaxf(a0x, a1x), a2x);
    float ymn = fminf(fminf(a0y, a1y), a2y);
    float ymx = fmaxf(fmaxf(a0y, a1y), a2y);
    sBB[f] = make_float4((xmn + 0.9375f)*64.0f - 0.5f,   // wmin
                         (xmx + 1.0625f)*64.0f - 0.5f,   // wmax
                         (0.9375f - ymx)*64.0f - 0.5f,   // hmin
                         (1.0625f - ymn)*64.0f - 0.5f);  // hmax
    __syncthreads();

    // one thread per 8x8 tile builds the compacted pair list (deterministic order)
    {
        const int tile = f;                 // 0..255
        const float tX0 = (float)((tile & 15) << 3);
        const float tY0 = (float)((tile >> 4) << 3);
        const float tX1 = tX0 + 7.0f;
        const float tY1 = tY0 + 7.0f;
        int* L = (int*)(ws + 16384) + ((b << 8) + tile)*132;
        int cnt = 0;
        for (int p = 0; p < 128; ++p) {
            float4 b1 = sBB[2*p], b2 = sBB[2*p+1];
            bool h1 = (b1.x <= tX1) && (b1.y >= tX0) && (b1.z <= tY1) && (b1.w >= tY0);
            bool h2 = (b2.x <= tX1) && (b2.y >= tX0) && (b2.z <= tY1) && (b2.w >= tY0);
            if (h1 || h2) L[1 + cnt++] = p;
        }
        L[0] = cnt;
    }
}

// grid 1024 = b*256 + tile(8x8px); block (64,8): lane = pixel, wave = strided list slice
__launch_bounds__(512)
__global__ void raster(const float* __restrict__ ws, float* __restrict__ out)
{
    __shared__ float sFD[4096];   // 16KB face table; reductions aliased in after loop

    const int t   = threadIdx.x;   // 0..63
    const int cy  = threadIdx.y;   // 0..7
    const int bid = blockIdx.x;
    const int b    = bid >> 8;
    const int tile = bid & 255;
    const int tx0 = (tile & 15) << 3;
    const int ty0 = (tile >> 4) << 3;

    // stage the per-batch face table: 4096 floats = 1024 float4, 2 per thread
    {
        const float4* src = (const float4*)(ws + (b << 12));
        float4* dst = (float4*)sFD;
        int tid = (cy << 6) + t;    // 0..511
        dst[tid]       = src[tid];
        dst[tid + 512] = src[tid + 512];
    }
    __syncthreads();

    const int w = tx0 + (t & 7);
    const int h = ty0 + (t >> 3);
    const float xs = ((w + 0.5f) * (1.0f/64.0f) - 1.0f) * SCV;
    const float ys = (1.0f - (h + 0.5f) * (1.0f/64.0f)) * SCV;
    const v2f PX = { xs, xs }, PY = { ys, ys };

    const v2f KGH_NEG = { -0.5f*KGAMV, -0.5f*KGAMV };
    const v2f KGH_POS = {  0.5f*KGAMV,  0.5f*KGAMV };
    const v2f ONE2 = { 1.0f, 1.0f };
    const v2f EPS2 = { 1e-8f, 1e-8f };

    const int* L = (const int*)(ws + 16384) + bid*132;
    const int cnt = rfl(L[0]);

    v2f aP = ONE2, aS = {0,0}, aR0 = {0,0}, aR1 = {0,0}, aR2 = {0,0};

    int k = cy;
    int p = (k < cnt) ? rfl(L[1 + k]) : 0;
    while (k < cnt) {
        const int kn = k + 8;
        const int pn = (kn < cnt) ? rfl(L[1 + kn]) : 0;   // prefetch next entry

        const float* c = sFD + p*STR;
#define LD(q) (*(const v2f*)(c + 2*(q)))
        v2f a0x = LD(0), a0y = LD(1);
        v2f e01x = LD(2), e01y = LD(3);
        v2f e12x = LD(4), e12y = LD(5);
        v2f ib01 = LD(6), ib12 = LD(7), ib20 = LD(8);
        v2f idn = LD(9);
        v2f z0 = LD(10), z1 = LD(11), z2 = LD(12);
        v2f cr = LD(13), cg = LD(14), cb = LD(15);
#undef LD
        v2f e20x = -(e01x + e12x), e20y = -(e01y + e12y);
        v2f g01x = e01x*ib01, g01y = e01y*ib01;
        v2f g12x = e12x*ib12, g12y = e12y*ib12;
        v2f g20x = e20x*ib20, g20y = e20y*ib20;

        // PH1: barycentrics + signed scaled sq-distance
        v2f pa0x = PX - a0x, pa0y = PY - a0y;
        v2f pa1x = pa0x - e01x, pa1y = pa0y - e01y;
        v2f pa2x = pa0x + e20x, pa2y = pa0y + e20y;
        v2f b0 = fma2(-e12y, pa1x, e12x*pa1y) * idn;
        v2f b1 = fma2(-e20y, pa2x, e20x*pa2y) * idn;
        v2f b2 = fma2(-e01y, pa0x, e01x*pa0y) * idn;

        v2f tt = med01_2(fma2(pa0x, g01x, pa0y*g01y));
        v2f dx = fma2(-tt, e01x, pa0x);
        v2f dy = fma2(-tt, e01y, pa0y);
        v2f ddA = fma2(dx, dx, dy*dy);
        tt = med01_2(fma2(pa1x, g12x, pa1y*g12y));
        dx = fma2(-tt, e12x, pa1x);
        dy = fma2(-tt, e12y, pa1y);
        v2f ddB = fma2(dx, dx, dy*dy);
        tt = med01_2(fma2(pa2x, g20x, pa2y*g20y));
        dx = fma2(-tt, e20x, pa2x);
        dy = fma2(-tt, e20y, pa2y);
        v2f ddC = fma2(dx, dx, dy*dy);

        float ddl = fminf(fminf(ddA.x, ddB.x), ddC.x);
        float ddh = fminf(fminf(ddA.y, ddB.y), ddC.y);
        float mxl = fmaxf(fmaxf(-b0.x, -b1.x), -b2.x);
        float mxh = fmaxf(fmaxf(-b0.y, -b1.y), -b2.y);
        v2f q = { copysignf(ddl, mxl), copysignf(ddh, mxh) };

        // PH2: sigmoid + softmax-weight accumulation
        v2f e2 = { ex2(q.x), ex2(q.y) };
        v2f den = e2 + ONE2;
        v2f prob = { rcpf(den.x), rcpf(den.y) };
        aP = fma2(-prob, aP, aP);

        v2f bc0 = med01_2(b0), bc1 = med01_2(b1), bc2 = med01_2(b2);
        v2f s = (bc0 + bc1) + (bc2 + EPS2);
        v2f zs = fma2(bc0, z0, fma2(bc1, z1, bc2*z2));
        v2f irs = { rcpf(s.x), rcpf(s.y) };
        v2f zq = fma2(zs*irs, KGH_NEG, KGH_POS);
        v2f ez = { ex2(__builtin_amdgcn_fmed3f(zq.x, 0.0f, KGAMV)),
                   ex2(__builtin_amdgcn_fmed3f(zq.y, 0.0f, KGAMV)) };
        v2f wgt = prob * ez;
        aS = aS + wgt;
        aR0 = fma2(wgt, cr, aR0);
        aR1 = fma2(wgt, cg, aR1);
        aR2 = fma2(wgt, cb, aR2);

        k = kn; p = pn;
    }

    // alias reduction arrays into the table LDS
    __syncthreads();
    float* red = sFD;   // [5][8][64]
    red[(0*8 + cy)*64 + t] = aP.x * aP.y;
    red[(1*8 + cy)*64 + t] = aS.x + aS.y;
    red[(2*8 + cy)*64 + t] = aR0.x + aR0.y;
    red[(3*8 + cy)*64 + t] = aR1.x + aR1.y;
    red[(4*8 + cy)*64 + t] = aR2.x + aR2.y;
    __syncthreads();

    if (cy == 0) {
        float P = 1.0f, St = 0.0f, r0 = 0.0f, r1 = 0.0f, r2 = 0.0f;
#pragma unroll
        for (int c2 = 0; c2 < 8; ++c2) {
            P  *= red[(0*8 + c2)*64 + t];
            St += red[(1*8 + c2)*64 + t];
            r0 += red[(2*8 + c2)*64 + t];
            r1 += red[(3*8 + c2)*64 + t];
            r2 += red[(4*8 + c2)*64 + t];
        }
        float iden = rcpf(St + 1.0f);   // background weight = exp2(0) = 1

        const int pix = h*IMG + w;
        out[b*16384 + pix] = 1.0f - P;
        float* rgb = out + 65536;
        rgb[(b*3 + 0)*16384 + pix] = r0 * iden;
        rgb[(b*3 + 1)*16384 + pix] = r1 * iden;
        rgb[(b*3 + 2)*16384 + pix] = r2 * iden;
    }
}

extern "C" void kernel_launch(void* const* d_in, const int* in_sizes, int n_in,
                              void* d_out, int out_size, void* d_ws, size_t ws_size,
                              hipStream_t stream)
{
    const float* verts  = (const float*)d_in[0];
    const int*   faces  = (const int*)d_in[1];
    const float* colors = (const float*)d_in[2];
    const float* eye    = (const float*)d_in[3];
    float* out = (float*)d_out;
    float* ws  = (float*)d_ws;   // rec 64KB @0, lists 540KB @16384 floats

    hipLaunchKernelGGL(prep_faces, dim3(4),    dim3(256), 0, stream,
                       verts, faces, colors, eye, ws);
    hipLaunchKernelGGL(raster,     dim3(1024), dim3(64, 8), 0, stream, ws, out);
}

// Round 10
// 33.349 us; speedup vs baseline: 1.6373x; 1.5935x over previous
//
#include <hip/hip_runtime.h>

#define NB 4
#define NV 256
#define NF 256
#define IMG 128
#define STR 32   // floats per face-PAIR record (16 slots x 2, 128B)

typedef float v2f __attribute__((ext_vector_type(2)));
typedef float v4f __attribute__((ext_vector_type(4)));

__device__ __forceinline__ float rcpf(float x) { return __builtin_amdgcn_rcpf(x); }
__device__ __forceinline__ float ex2(float x)  { return __builtin_amdgcn_exp2f(x); }
__device__ __forceinline__ float med01(float x) { return __builtin_amdgcn_fmed3f(x, 0.0f, 1.0f); }
__device__ __forceinline__ v2f med01_2(v2f v) { return (v2f){ med01(v.x), med01(v.y) }; }
__device__ __forceinline__ v2f fma2(v2f a, v2f b, v2f c) { return __builtin_elementwise_fma(a, b, c); }
__device__ __forceinline__ v2f lo2(v4f q) { return __builtin_shufflevector(q, q, 0, 1); }
__device__ __forceinline__ v2f hi2(v4f q) { return __builtin_shufflevector(q, q, 2, 3); }

#define SCV   120.11224139682566f    // sqrt((1/SIGMA)*log2(e))
#define ISC2  6.931471805599453e-05f // 1/KSIG
#define KGAMV 14.426950408889634f    // (1/GAMMA)*log2(e)

// pair-interleaved record, slot k of face f at [2k + (f&1)]:
//  0 a0x*SC 1 a0y*SC | 2 e01x*SC 3 e01y*SC | 4 e12x*SC 5 e12y*SC | 6 ib01' 7 ib12'
//  8 ib20' 9 idn'    | 10 z0 11 z1 | 12 z2 13 cr | 14 cg 15 cb     (' = /KSIG)

__global__ void prep_faces(const float* __restrict__ verts,
                           const int* __restrict__ faces,
                           const float* __restrict__ colors,
                           const float* __restrict__ eye,
                           float* __restrict__ ws)
{
    const int b = blockIdx.x;      // 0..3
    const int f = threadIdx.x;     // 0..255

    const float fpj = 1.7320508075688772f;
    const float p22 = -1.0202020202020203f;
    const float p23 = -0.20202020202020202f;

    float ex = eye[b*3+0], ey = eye[b*3+1], ez = eye[b*3+2];
    float en  = sqrtf(ex*ex + ey*ey + ez*ez);
    float izn = 1.0f / (en + 1e-8f);
    float zx = ex*izn, zy = ey*izn, zz = ez*izn;
    float cn  = sqrtf(zz*zz + zx*zx);
    float ixn = 1.0f / (cn + 1e-8f);
    float xx = zz*ixn, xy = 0.0f, xz = -zx*ixn;
    float yx = zy*xz - zz*xy;
    float yy = zz*xx - zx*xz;
    float yz = zx*xy - zy*xx;
    float tx = -(xx*ex + xy*ey + xz*ez);
    float ty = -(yx*ex + yy*ey + yz*ez);
    float tz = -(zx*ex + zy*ey + zz*ez);

    int i0 = faces[f*3+0], i1 = faces[f*3+1], i2 = faces[f*3+2];
    int idx[3] = { i0, i1, i2 };

    float ax[3], ay[3], az[3];
#pragma unroll
    for (int k = 0; k < 3; ++k) {
        const float* v = verts + (b*NV + idx[k])*3;
        float vx = v[0], vy = v[1], vz = v[2];
        float cx  = fpj*(xx*vx + xy*vy + xz*vz + tx);
        float cyv = fpj*(yx*vx + yy*vy + yz*vz + ty);
        float zv  = zx*vx + zy*vy + zz*vz + tz;
        float cz  = p22*zv + p23;
        float cw  = -zv;
        float iw  = 1.0f / (cw + 1e-8f);
        ax[k] = cx*iw; ay[k] = cyv*iw; az[k] = cz*iw;
    }

    float a0x = ax[0], a0y = ay[0];
    float a1x = ax[1], a1y = ay[1];
    float a2x = ax[2], a2y = ay[2];

    float e01x = a1x - a0x, e01y = a1y - a0y;
    float e12x = a2x - a1x, e12y = a2y - a1y;
    float e20x = a0x - a2x, e20y = a0y - a2y;

    float area  = e01x*(a2y - a0y) - e01y*(a2x - a0x);
    float denom = area + (area >= 0.0f ? 1e-12f : -1e-12f);
    float idn   = 1.0f / denom;

    float ib01 = 1.0f / (e01x*e01x + e01y*e01y + 1e-12f);
    float ib12 = 1.0f / (e12x*e12x + e12y*e12y + 1e-12f);
    float ib20 = 1.0f / (e20x*e20x + e20y*e20y + 1e-12f);

    const float third = (1.0f/3.0f);
    float cr = (colors[(b*NV+i0)*3+0] + colors[(b*NV+i1)*3+0] + colors[(b*NV+i2)*3+0]) * third;
    float cg = (colors[(b*NV+i0)*3+1] + colors[(b*NV+i1)*3+1] + colors[(b*NV+i2)*3+1]) * third;
    float cb = (colors[(b*NV+i0)*3+2] + colors[(b*NV+i1)*3+2] + colors[(b*NV+i2)*3+2]) * third;

    float* o = ws + (b*128 + (f >> 1))*STR + (f & 1);
    o[ 0]=a0x*SCV;   o[ 2]=a0y*SCV;
    o[ 4]=e01x*SCV;  o[ 6]=e01y*SCV;
    o[ 8]=e12x*SCV;  o[10]=e12y*SCV;
    o[12]=ib01*ISC2; o[14]=ib12*ISC2; o[16]=ib20*ISC2;
    o[18]=idn*ISC2;
    o[20]=az[0]; o[22]=az[1]; o[24]=az[2];
    o[26]=cr;   o[28]=cg;   o[30]=cb;
}

// grid 1024 = b*256 + tile(8x8px); block (64,8): lane = pixel, wave cy = 16-pair chunk
__launch_bounds__(512, 6)
__global__ void raster(const float* __restrict__ ws, float* __restrict__ out)
{
    __shared__ float sFD[4096];   // 16KB table; reduction arrays aliased after loop

    const int t   = threadIdx.x;   // 0..63
    const int cy  = threadIdx.y;   // 0..7
    const int bid = blockIdx.x;
    const int b    = bid >> 8;
    const int tile = bid & 255;
    const int tx0 = (tile & 15) << 3;
    const int ty0 = (tile >> 4) << 3;

    // stage per-batch face table: 4096 floats = 1024 float4, 2 per thread
    {
        const float4* src = (const float4*)(ws + (b << 12));
        float4* dst = (float4*)sFD;
        int tid = (cy << 6) + t;    // 0..511
        dst[tid]       = src[tid];
        dst[tid + 512] = src[tid + 512];
    }
    __syncthreads();

    const int w = tx0 + (t & 7);
    const int h = ty0 + (t >> 3);
    const float xs = ((w + 0.5f) * (1.0f/64.0f) - 1.0f) * SCV;
    const float ys = (1.0f - (h + 0.5f) * (1.0f/64.0f)) * SCV;
    const v2f PX = { xs, xs }, PY = { ys, ys };

    const v2f KGH_NEG = { -0.5f*KGAMV, -0.5f*KGAMV };
    const v2f KGH_POS = {  0.5f*KGAMV,  0.5f*KGAMV };
    const v2f ONE2 = { 1.0f, 1.0f };
    const v2f EPS2 = { 1e-8f, 1e-8f };

    const float* fc = sFD + (cy << 4)*STR;   // this wave's 16 pairs

    v2f aP = ONE2, aS = {0,0}, aR0 = {0,0}, aR1 = {0,0}, aR2 = {0,0};

#pragma unroll 2
    for (int i = 0; i < 16; ++i) {
        const float* c = fc + i*STR;
        // 8 x ds_read_b128 (wave-uniform broadcast)
        v4f q0 = *(const v4f*)(c +  0);
        v4f q1 = *(const v4f*)(c +  4);
        v4f q2 = *(const v4f*)(c +  8);
        v4f q3 = *(const v4f*)(c + 12);
        v4f q4 = *(const v4f*)(c + 16);
        v4f q5 = *(const v4f*)(c + 20);
        v4f q6 = *(const v4f*)(c + 24);
        v4f q7 = *(const v4f*)(c + 28);
        v2f a0x = lo2(q0), a0y = hi2(q0);
        v2f e01x = lo2(q1), e01y = hi2(q1);
        v2f e12x = lo2(q2), e12y = hi2(q2);
        v2f ib01 = lo2(q3), ib12 = hi2(q3);
        v2f ib20 = lo2(q4), idn  = hi2(q4);
        v2f z0 = lo2(q5), z1 = hi2(q5);
        v2f z2 = lo2(q6), cr = hi2(q6);
        v2f cg = lo2(q7), cb = hi2(q7);

        v2f e20x = -(e01x + e12x), e20y = -(e01y + e12y);
        v2f g01x = e01x*ib01, g01y = e01y*ib01;
        v2f g12x = e12x*ib12, g12y = e12y*ib12;
        v2f g20x = e20x*ib20, g20y = e20y*ib20;

        // PH1: barycentrics (b2 = 1-b0-b1) + signed scaled sq-distance
        v2f pa0x = PX - a0x, pa0y = PY - a0y;
        v2f pa1x = pa0x - e01x, pa1y = pa0y - e01y;
        v2f pa2x = pa0x + e20x, pa2y = pa0y + e20y;
        v2f b0 = fma2(-e12y, pa1x, e12x*pa1y) * idn;
        v2f b1 = fma2(-e20y, pa2x, e20x*pa2y) * idn;
        v2f b2 = (ONE2 - b0) - b1;

        v2f tt = med01_2(fma2(pa0x, g01x, pa0y*g01y));
        v2f dx = fma2(-tt, e01x, pa0x);
        v2f dy = fma2(-tt, e01y, pa0y);
        v2f ddA = fma2(dx, dx, dy*dy);
        tt = med01_2(fma2(pa1x, g12x, pa1y*g12y));
        dx = fma2(-tt, e12x, pa1x);
        dy = fma2(-tt, e12y, pa1y);
        v2f ddB = fma2(dx, dx, dy*dy);
        tt = med01_2(fma2(pa2x, g20x, pa2y*g20y));
        dx = fma2(-tt, e20x, pa2x);
        dy = fma2(-tt, e20y, pa2y);
        v2f ddC = fma2(dx, dx, dy*dy);

        v2f dd = __builtin_elementwise_min(__builtin_elementwise_min(ddA, ddB), ddC);
        v2f mx = __builtin_elementwise_max(__builtin_elementwise_max(-b0, -b1), -b2);
        v2f q  = { copysignf(dd.x, mx.x), copysignf(dd.y, mx.y) };

        // PH2: sigmoid + softmax weight
        v2f e2 = { ex2(q.x), ex2(q.y) };
        v2f den = e2 + ONE2;
        v2f prob = { rcpf(den.x), rcpf(den.y) };
        aP = fma2(-prob, aP, aP);

        v2f bc0 = med01_2(b0), bc1 = med01_2(b1), bc2 = med01_2(b2);
        v2f s = (bc0 + bc1) + (bc2 + EPS2);
        v2f zs = fma2(bc0, z0, fma2(bc1, z1, bc2*z2));
        v2f irs = { rcpf(s.x), rcpf(s.y) };
        v2f zq = fma2(zs*irs, KGH_NEG, KGH_POS);
        v2f ez = { ex2(__builtin_amdgcn_fmed3f(zq.x, 0.0f, KGAMV)),
                   ex2(__builtin_amdgcn_fmed3f(zq.y, 0.0f, KGAMV)) };
        v2f wgt = prob * ez;
        aS  = aS + wgt;
        aR0 = fma2(wgt, cr, aR0);
        aR1 = fma2(wgt, cg, aR1);
        aR2 = fma2(wgt, cb, aR2);
    }

    // alias reduction arrays into the table LDS
    __syncthreads();
    float* red = sFD;   // [5][8][64] = 10KB
    red[(0*8 + cy)*64 + t] = aP.x * aP.y;
    red[(1*8 + cy)*64 + t] = aS.x + aS.y;
    red[(2*8 + cy)*64 + t] = aR0.x + aR0.y;
    red[(3*8 + cy)*64 + t] = aR1.x + aR1.y;
    red[(4*8 + cy)*64 + t] = aR2.x + aR2.y;
    __syncthreads();

    if (cy == 0) {
        float P = 1.0f, St = 0.0f, r0 = 0.0f, r1 = 0.0f, r2 = 0.0f;
#pragma unroll
        for (int c2 = 0; c2 < 8; ++c2) {
            P  *= red[(0*8 + c2)*64 + t];
            St += red[(1*8 + c2)*64 + t];
            r0 += red[(2*8 + c2)*64 + t];
            r1 += red[(3*8 + c2)*64 + t];
            r2 += red[(4*8 + c2)*64 + t];
        }
        float iden = rcpf(St + 1.0f);   // background weight = exp2(0) = 1

        const int pix = h*IMG + w;
        out[b*16384 + pix] = 1.0f - P;
        float* rgb = out + 65536;
        rgb[(b*3 + 0)*16384 + pix] = r0 * iden;
        rgb[(b*3 + 1)*16384 + pix] = r1 * iden;
        rgb[(b*3 + 2)*16384 + pix] = r2 * iden;
    }
}

extern "C" void kernel_launch(void* const* d_in, const int* in_sizes, int n_in,
                              void* d_out, int out_size, void* d_ws, size_t ws_size,
                              hipStream_t stream)
{
    const float* verts  = (const float*)d_in[0];
    const int*   faces  = (const int*)d_in[1];
    const float* colors = (const float*)d_in[2];
    const float* eye    = (const float*)d_in[3];
    float* out = (float*)d_out;
    float* ws  = (float*)d_ws;   // 64 KB face records

    hipLaunchKernelGGL(prep_faces, dim3(4),    dim3(256),   0, stream,
                       verts, faces, colors, eye, ws);
    hipLaunchKernelGGL(raster,     dim3(1024), dim3(64, 8), 0, stream, ws, out);
}